// Round 1
// baseline (852.188 us; speedup 1.0000x reference)
//
#include <hip/hip_runtime.h>
#include <math.h>

#define DIM_ 2048
#define HID_ 8192
#define SEQ_ 2048
#define BATCH_ 2
#define TOK_ (BATCH_*SEQ_)

typedef __attribute__((ext_vector_type(4))) float f32x4;
typedef __attribute__((ext_vector_type(8))) __bf16 bf16x8;
typedef __attribute__((ext_vector_type(4))) short s16x4;

__device__ __forceinline__ short f2bf(float f) {
  union { float f; unsigned u; } v; v.f = f;
  unsigned r = v.u + 0x7FFFu + ((v.u >> 16) & 1u);
  return (short)(r >> 16);
}

// ---------------------------------------------------------------------------
// GEMM: C[M,N] = A[M,K](bf16) @ B^T  where B is stored N x K (bf16, row-major)
// 128x128 tile, BK=32, 4 waves (2x2 of 64x64), mfma_f32_16x16x32_bf16.
// EPI: 0 = bias -> bf16 out; 1 = raw fp32 out; 2 = bias+exact GELU -> bf16;
//      3 = bias + aux(fp32 residual, same MxN) -> fp32 out.
// ---------------------------------------------------------------------------
template<int EPI>
__global__ __launch_bounds__(256)
void gemm_bt(const short* __restrict__ A, const short* __restrict__ B,
             void* __restrict__ Cv, const float* __restrict__ bias,
             const float* __restrict__ aux,
             int M, int N, int K,
             long long sA, long long sB, long long sC)
{
  __shared__ __align__(16) short As[128*32];
  __shared__ __align__(16) short Bs[128*32];
  const int lane = threadIdx.x & 63;
  const int wave = threadIdx.x >> 6;
  const int wr = wave >> 1, wc = wave & 1;
  const int tm = blockIdx.y << 7, tn = blockIdx.x << 7;
  const int z = blockIdx.z;
  A += (long long)z * sA;
  B += (long long)z * sB;

  // staging geometry: chunk = wave*2+c covers 16 rows; lane l writes bytes l*16
  const int srow = lane >> 2;          // row within 16-row chunk
  const int scol = (lane & 3) << 3;    // k-element offset (8 bf16 = 16B)
  const short* Abase = A + (long long)(tm + (wave << 5) + srow) * K + scol;
  const short* Bbase = B + (long long)(tn + (wave << 5) + srow) * K + scol;

  f32x4 acc[4][4] = {};

  const int arow = (wr << 6) + (lane & 15);
  const int brow = (wc << 6) + (lane & 15);
  const int kb   = (lane >> 4) << 3;   // k element offset 0/8/16/24

  for (int k0 = 0; k0 < K; k0 += 32) {
    #pragma unroll
    for (int c = 0; c < 2; ++c) {
      __builtin_amdgcn_global_load_lds(
          (const __attribute__((address_space(1))) void*)(Abase + (long long)(c << 4) * K + k0),
          (__attribute__((address_space(3))) void*)(As + ((wave << 1) + c) * 512), 16, 0, 0);
      __builtin_amdgcn_global_load_lds(
          (const __attribute__((address_space(1))) void*)(Bbase + (long long)(c << 4) * K + k0),
          (__attribute__((address_space(3))) void*)(Bs + ((wave << 1) + c) * 512), 16, 0, 0);
    }
    __syncthreads();   // drains vmcnt before ds_read
    bf16x8 af[4], bfr[4];
    #pragma unroll
    for (int i = 0; i < 4; ++i) af[i]  = *(const bf16x8*)&As[(arow + i * 16) * 32 + kb];
    #pragma unroll
    for (int i = 0; i < 4; ++i) bfr[i] = *(const bf16x8*)&Bs[(brow + i * 16) * 32 + kb];
    #pragma unroll
    for (int mi = 0; mi < 4; ++mi)
      #pragma unroll
      for (int ni = 0; ni < 4; ++ni)
        acc[mi][ni] = __builtin_amdgcn_mfma_f32_16x16x32_bf16(af[mi], bfr[ni], acc[mi][ni], 0, 0, 0);
    __syncthreads();   // protect LDS before next stage
  }

  // epilogue: C/D layout col = lane&15, row = (lane>>4)*4 + reg (m89/m91 verified)
  const int row0 = tm + (wr << 6) + ((lane >> 4) << 2);
  const int col0 = tn + (wc << 6) + (lane & 15);

  #pragma unroll
  for (int mi = 0; mi < 4; ++mi) {
    #pragma unroll
    for (int j = 0; j < 4; ++j) {
      const int row = row0 + mi * 16 + j;
      #pragma unroll
      for (int ni = 0; ni < 4; ++ni) {
        const int col = col0 + ni * 16;
        float v = acc[mi][ni][j];
        if (EPI == 1) {
          float* C = (float*)Cv + (long long)z * sC;
          C[(long long)row * N + col] = v;
        } else if (EPI == 0) {
          v += bias[col];
          short* C = (short*)Cv + (long long)z * sC;
          C[(long long)row * N + col] = f2bf(v);
        } else if (EPI == 2) {
          v += bias[col];
          v = 0.5f * v * (1.0f + erff(v * 0.70710678118654752f));  // exact GELU
          short* C = (short*)Cv + (long long)z * sC;
          C[(long long)row * N + col] = f2bf(v);
        } else { // EPI == 3
          v += bias[col] + aux[(long long)row * N + col];
          float* C = (float*)Cv + (long long)z * sC;
          C[(long long)row * N + col] = v;
        }
      }
    }
  }
}

// ---------------------------------------------------------------------------
// LayerNorm: out_bf16[row] = LN(x[row] (+ res[row])) * g + b   (row = 2048 f32)
// ---------------------------------------------------------------------------
__global__ __launch_bounds__(256)
void ln_kernel(const float* __restrict__ x, const float* __restrict__ res,
               const float* __restrict__ g, const float* __restrict__ b,
               short* __restrict__ out, int hasres)
{
  const int row = blockIdx.x;
  const int tid = threadIdx.x;
  const float4* X = (const float4*)x + (long long)row * 512;
  float4 v0 = X[tid], v1 = X[tid + 256];
  if (hasres) {
    const float4* R = (const float4*)res + (long long)row * 512;
    float4 r0 = R[tid], r1 = R[tid + 256];
    v0.x += r0.x; v0.y += r0.y; v0.z += r0.z; v0.w += r0.w;
    v1.x += r1.x; v1.y += r1.y; v1.z += r1.z; v1.w += r1.w;
  }
  float s1 = v0.x + v0.y + v0.z + v0.w + v1.x + v1.y + v1.z + v1.w;
  float s2 = v0.x*v0.x + v0.y*v0.y + v0.z*v0.z + v0.w*v0.w
           + v1.x*v1.x + v1.y*v1.y + v1.z*v1.z + v1.w*v1.w;
  #pragma unroll
  for (int o = 32; o > 0; o >>= 1) { s1 += __shfl_xor(s1, o); s2 += __shfl_xor(s2, o); }
  __shared__ float red[8];
  if ((tid & 63) == 0) { red[tid >> 6] = s1; red[4 + (tid >> 6)] = s2; }
  __syncthreads();
  s1 = red[0] + red[1] + red[2] + red[3];
  s2 = red[4] + red[5] + red[6] + red[7];
  const float mean = s1 * (1.0f / 2048.0f);
  const float var  = s2 * (1.0f / 2048.0f) - mean * mean;
  const float rstd = rsqrtf(var + 1e-5f);
  const float4* G  = (const float4*)g;
  const float4* Bb = (const float4*)b;
  float4 g0 = G[tid], g1 = G[tid + 256], b0 = Bb[tid], b1 = Bb[tid + 256];
  s16x4 o0, o1;
  o0[0] = f2bf((v0.x - mean) * rstd * g0.x + b0.x);
  o0[1] = f2bf((v0.y - mean) * rstd * g0.y + b0.y);
  o0[2] = f2bf((v0.z - mean) * rstd * g0.z + b0.z);
  o0[3] = f2bf((v0.w - mean) * rstd * g0.w + b0.w);
  o1[0] = f2bf((v1.x - mean) * rstd * g1.x + b1.x);
  o1[1] = f2bf((v1.y - mean) * rstd * g1.y + b1.y);
  o1[2] = f2bf((v1.z - mean) * rstd * g1.z + b1.z);
  o1[3] = f2bf((v1.w - mean) * rstd * g1.w + b1.w);
  *(s16x4*)&out[(long long)row * 2048 + tid * 4]        = o0;
  *(s16x4*)&out[(long long)row * 2048 + 1024 + tid * 4] = o1;
}

// ---------------------------------------------------------------------------
// Softmax over scores rows: probs_bf16 = softmax(scores*scale + mask[q])
// ---------------------------------------------------------------------------
__global__ __launch_bounds__(256)
void softmax_kernel(const float* __restrict__ scores, const float* __restrict__ mask,
                    short* __restrict__ probs)
{
  const long long row = blockIdx.x;          // b*SEQ + q
  const int q  = blockIdx.x & (SEQ_ - 1);
  const int tid = threadIdx.x;
  const float scale = 0.022097086912079608f; // 1/sqrt(2048)
  const float4* S  = (const float4*)scores + row * 512;
  const float4* Mk = (const float4*)mask + (long long)q * 512;
  float4 v0 = S[tid], v1 = S[tid + 256];
  float4 m0 = Mk[tid], m1 = Mk[tid + 256];
  float a[8] = { v0.x*scale + m0.x, v0.y*scale + m0.y, v0.z*scale + m0.z, v0.w*scale + m0.w,
                 v1.x*scale + m1.x, v1.y*scale + m1.y, v1.z*scale + m1.z, v1.w*scale + m1.w };
  float mx = a[0];
  #pragma unroll
  for (int i = 1; i < 8; ++i) mx = fmaxf(mx, a[i]);
  #pragma unroll
  for (int o = 32; o > 0; o >>= 1) mx = fmaxf(mx, __shfl_xor(mx, o));
  __shared__ float red[8];
  if ((tid & 63) == 0) red[tid >> 6] = mx;
  __syncthreads();
  mx = fmaxf(fmaxf(red[0], red[1]), fmaxf(red[2], red[3]));
  float e[8], sum = 0.f;
  #pragma unroll
  for (int i = 0; i < 8; ++i) { e[i] = __expf(a[i] - mx); sum += e[i]; }
  #pragma unroll
  for (int o = 32; o > 0; o >>= 1) sum += __shfl_xor(sum, o);
  if ((tid & 63) == 0) red[4 + (tid >> 6)] = sum;
  __syncthreads();
  sum = red[4] + red[5] + red[6] + red[7];
  const float inv = 1.0f / sum;
  s16x4 o0, o1;
  #pragma unroll
  for (int i = 0; i < 4; ++i) o0[i] = f2bf(e[i] * inv);
  #pragma unroll
  for (int i = 0; i < 4; ++i) o1[i] = f2bf(e[4 + i] * inv);
  probs += row * 2048;
  *(s16x4*)&probs[tid * 4]        = o0;
  *(s16x4*)&probs[1024 + tid * 4] = o1;
}

// ---------------------------------------------------------------------------
// fp32 (R,C) -> bf16 (C,R) transpose-convert (weights)
// ---------------------------------------------------------------------------
__global__ __launch_bounds__(256)
void cvt_transpose_kernel(const float* __restrict__ in, short* __restrict__ out,
                          int R, int C)
{
  __shared__ float t[32][33];
  const int tx = threadIdx.x & 31, ty = threadIdx.x >> 5;
  const int r0 = blockIdx.y << 5, c0 = blockIdx.x << 5;
  #pragma unroll
  for (int i = 0; i < 32; i += 8)
    t[ty + i][tx] = in[(long long)(r0 + ty + i) * C + c0 + tx];
  __syncthreads();
  #pragma unroll
  for (int i = 0; i < 32; i += 8)
    out[(long long)(c0 + ty + i) * R + r0 + tx] = f2bf(t[tx][ty + i]);
}

// bf16 (z,R,C) -> bf16 (z,C,R) transpose (V)
__global__ __launch_bounds__(256)
void transpose_bf16_kernel(const short* __restrict__ in, short* __restrict__ out,
                           int R, int C)
{
  __shared__ short t[32][33];
  in  += (long long)blockIdx.z * R * C;
  out += (long long)blockIdx.z * R * C;
  const int tx = threadIdx.x & 31, ty = threadIdx.x >> 5;
  const int r0 = blockIdx.y << 5, c0 = blockIdx.x << 5;
  #pragma unroll
  for (int i = 0; i < 32; i += 8)
    t[ty + i][tx] = in[(long long)(r0 + ty + i) * C + c0 + tx];
  __syncthreads();
  #pragma unroll
  for (int i = 0; i < 32; i += 8)
    out[(long long)(c0 + ty + i) * R + r0 + tx] = t[tx][ty + i];
}

// ---------------------------------------------------------------------------
extern "C" void kernel_launch(void* const* d_in, const int* in_sizes, int n_in,
                              void* d_out, int out_size, void* d_ws, size_t ws_size,
                              hipStream_t stream)
{
  const float* x    = (const float*)d_in[0];
  const float* mask = (const float*)d_in[1];
  const float* wq   = (const float*)d_in[4];
  const float* bq   = (const float*)d_in[5];
  const float* wk   = (const float*)d_in[6];
  const float* bk   = (const float*)d_in[7];
  const float* wv   = (const float*)d_in[8];
  const float* bv   = (const float*)d_in[9];
  const float* g1   = (const float*)d_in[10];
  const float* b1   = (const float*)d_in[11];
  const float* g2   = (const float*)d_in[12];
  const float* b2   = (const float*)d_in[13];
  const float* w1   = (const float*)d_in[14];
  const float* bw1  = (const float*)d_in[15];
  const float* w2   = (const float*)d_in[16];
  const float* bw2  = (const float*)d_in[17];
  float* out = (float*)d_out;

  char* p = (char*)d_ws;
  auto take = [&](size_t bytes) { char* r = p; p += (bytes + 255) & ~(size_t)255; return r; };
  short* wqT   = (short*)take((size_t)DIM_ * DIM_ * 2);
  short* wkT   = (short*)take((size_t)DIM_ * DIM_ * 2);
  short* wvT   = (short*)take((size_t)DIM_ * DIM_ * 2);
  short* w1T   = (short*)take((size_t)DIM_ * HID_ * 2);   // (HID,DIM) bf16
  short* w2T   = (short*)take((size_t)HID_ * DIM_ * 2);   // (DIM,HID) bf16
  short* h_bf  = (short*)take((size_t)TOK_ * DIM_ * 2);   // reused as h2
  short* qb    = (short*)take((size_t)TOK_ * DIM_ * 2);   // q/k/v/vT region reused as ffn1
  short* kb    = (short*)take((size_t)TOK_ * DIM_ * 2);
  short* vb    = (short*)take((size_t)TOK_ * DIM_ * 2);
  short* vT    = (short*)take((size_t)TOK_ * DIM_ * 2);
  float* scores= (float*)take((size_t)BATCH_ * SEQ_ * SEQ_ * 4); // reused as attn_out
  short* attn  = (short*)take((size_t)BATCH_ * SEQ_ * SEQ_ * 2);
  short* ffn1  = qb;          // 64MB alias over q/k/v/vT (dead after PV)
  float* attno = scores;      // alias over scores (dead after softmax)
  short* h2    = h_bf;        // alias over h (dead after QKV)

  const dim3 blk(256);
  // weight convert+transpose -> N x K bf16
  cvt_transpose_kernel<<<dim3(DIM_/32, DIM_/32), blk, 0, stream>>>(wq, wqT, DIM_, DIM_);
  cvt_transpose_kernel<<<dim3(DIM_/32, DIM_/32), blk, 0, stream>>>(wk, wkT, DIM_, DIM_);
  cvt_transpose_kernel<<<dim3(DIM_/32, DIM_/32), blk, 0, stream>>>(wv, wvT, DIM_, DIM_);
  cvt_transpose_kernel<<<dim3(HID_/32, DIM_/32), blk, 0, stream>>>(w1, w1T, DIM_, HID_);
  cvt_transpose_kernel<<<dim3(DIM_/32, HID_/32), blk, 0, stream>>>(w2, w2T, HID_, DIM_);
  // LN1
  ln_kernel<<<TOK_, blk, 0, stream>>>(x, nullptr, g1, b1, h_bf, 0);
  // QKV
  gemm_bt<0><<<dim3(DIM_/128, TOK_/128, 1), blk, 0, stream>>>(h_bf, wqT, qb, bq, nullptr, TOK_, DIM_, DIM_, 0, 0, 0);
  gemm_bt<0><<<dim3(DIM_/128, TOK_/128, 1), blk, 0, stream>>>(h_bf, wkT, kb, bk, nullptr, TOK_, DIM_, DIM_, 0, 0, 0);
  gemm_bt<0><<<dim3(DIM_/128, TOK_/128, 1), blk, 0, stream>>>(h_bf, wvT, vb, bv, nullptr, TOK_, DIM_, DIM_, 0, 0, 0);
  // scores = q @ k^T (batched), fp32
  gemm_bt<1><<<dim3(SEQ_/128, SEQ_/128, BATCH_), blk, 0, stream>>>(
      qb, kb, scores, nullptr, nullptr, SEQ_, SEQ_, DIM_,
      (long long)SEQ_ * DIM_, (long long)SEQ_ * DIM_, (long long)SEQ_ * SEQ_);
  // softmax(scale + mask) -> bf16 probs
  softmax_kernel<<<BATCH_ * SEQ_, blk, 0, stream>>>(scores, mask, attn);
  // V transpose: (B,S,D) -> (B,D,S)
  transpose_bf16_kernel<<<dim3(DIM_/32, SEQ_/32, BATCH_), blk, 0, stream>>>(vb, vT, SEQ_, DIM_);
  // attn_out = probs @ V (batched), fp32
  gemm_bt<1><<<dim3(DIM_/128, SEQ_/128, BATCH_), blk, 0, stream>>>(
      attn, vT, attno, nullptr, nullptr, SEQ_, DIM_, SEQ_,
      (long long)SEQ_ * SEQ_, (long long)DIM_ * SEQ_, (long long)SEQ_ * DIM_);
  // LN2 over x + attn_out
  ln_kernel<<<TOK_, blk, 0, stream>>>(x, attno, g2, b2, h2, 1);
  // FFN1: gelu(h2 @ w1 + b1) -> bf16
  gemm_bt<2><<<dim3(HID_/128, TOK_/128, 1), blk, 0, stream>>>(h2, w1T, ffn1, bw1, nullptr, TOK_, HID_, DIM_, 0, 0, 0);
  // FFN2: x + (ffn1 @ w2 + b2) -> fp32 d_out
  gemm_bt<3><<<dim3(DIM_/128, TOK_/128, 1), blk, 0, stream>>>(ffn1, w2T, out, bw2, x, TOK_, DIM_, HID_, 0, 0, 0);
}

// Round 3
// 641.619 us; speedup vs baseline: 1.3282x; 1.3282x over previous
//
#include <hip/hip_runtime.h>
#include <math.h>

#define DIM_ 2048
#define HID_ 8192
#define SEQ_ 2048
#define BATCH_ 2
#define TOK_ (BATCH_*SEQ_)

typedef __attribute__((ext_vector_type(4))) float f32x4;
typedef __attribute__((ext_vector_type(8))) __bf16 bf16x8;
typedef __attribute__((ext_vector_type(4))) unsigned int u32x4;
typedef __attribute__((ext_vector_type(4))) short s16x4;
typedef __attribute__((address_space(3))) short* lds_sp;

__device__ __forceinline__ short f2bf(float f) {
  union { float f; unsigned u; } v; v.f = f;
  unsigned r = v.u + 0x7FFFu + ((v.u >> 16) & 1u);
  return (short)(r >> 16);
}

__device__ __forceinline__ f32x4 mfma16(u32x4 a, u32x4 b, f32x4 c) {
  return __builtin_amdgcn_mfma_f32_16x16x32_bf16(
      __builtin_bit_cast(bf16x8, a), __builtin_bit_cast(bf16x8, b), c, 0, 0, 0);
}

// ---------------------------------------------------------------------------
// Deep-pipelined GEMM, 128x256 tile, BK=64, 8 waves (2M x 4N), 64x64/wave.
// C[M,N] = A[M,K](bf16,lda) @ B^T, B stored N x K (bf16,ldb).
// 3-slot K-tile rotation (A 3x16KB, B 3x32KB = 144KB LDS): read tile t from
// slot t%3, stage tile t+2 into slot (t-1)%3 (its reads finished >=1 barrier
// ago -> no WAR race; RAW protected by counted vmcnt(6), never drained to 0).
// T2 slot-XOR swizzle (pre-swizzled global source, swizzled ds_read).
// T5 setprio around 16-MFMA clusters. T1 bijective XCD swizzle.
// EPI: 0 bias->bf16 | 1 raw fp32 | 2 bias+GELU->bf16 | 3 bias+aux ->fp32
// ---------------------------------------------------------------------------
#define DSR(dst, addr) asm volatile("ds_read_b128 %0, %1" : "=v"(dst) : "v"(addr))

#define RD_A(mlo, slot) do { \
  const unsigned ab_ = aBase + (unsigned)(slot)*16384u + (mlo)*2048u; \
  DSR(af[0][0], ab_ + offk0);         DSR(af[0][1], ab_ + offk1); \
  DSR(af[1][0], ab_ + 2048u + offk0); DSR(af[1][1], ab_ + 2048u + offk1); \
} while(0)

#define RD_B(slot) do { \
  const unsigned bb_ = bBase + (unsigned)(slot)*32768u; \
  DSR(bfr[0][0], bb_ + offk0);         DSR(bfr[0][1], bb_ + offk1); \
  DSR(bfr[1][0], bb_ + 2048u + offk0); DSR(bfr[1][1], bb_ + 2048u + offk1); \
  DSR(bfr[2][0], bb_ + 4096u + offk0); DSR(bfr[2][1], bb_ + 4096u + offk1); \
  DSR(bfr[3][0], bb_ + 6144u + offk0); DSR(bfr[3][1], bb_ + 6144u + offk1); \
} while(0)

#define MM(mlo) do { \
  _Pragma("unroll") \
  for (int n_ = 0; n_ < 4; ++n_) { \
    acc[(mlo)][n_]   = mfma16(af[0][0], bfr[n_][0], acc[(mlo)][n_]); \
    acc[(mlo)][n_]   = mfma16(af[0][1], bfr[n_][1], acc[(mlo)][n_]); \
    acc[(mlo)+1][n_] = mfma16(af[1][0], bfr[n_][0], acc[(mlo)+1][n_]); \
    acc[(mlo)+1][n_] = mfma16(af[1][1], bfr[n_][1], acc[(mlo)+1][n_]); \
  } \
} while(0)

#define BARv()  __builtin_amdgcn_s_barrier()
#define LGKM0() do { asm volatile("s_waitcnt lgkmcnt(0)" ::: "memory"); \
                     __builtin_amdgcn_sched_barrier(0); } while(0)
#define LGKM8() asm volatile("s_waitcnt lgkmcnt(8)" ::: "memory")
#define VM6()   asm volatile("s_waitcnt vmcnt(6)" ::: "memory")

template<int EPI>
__global__ __launch_bounds__(512, 2)
void gemm8p(const short* __restrict__ A, const short* __restrict__ B,
            void* __restrict__ Cv, const float* __restrict__ bias,
            const float* __restrict__ aux,
            int M, int N, int K, int lda, int ldb, int ldc,
            long long sA, long long sB, long long sC)
{
  __shared__ __align__(16) short As[3*128*64];   // 48 KB (3 slots)
  __shared__ __align__(16) short Bs[3*256*64];   // 96 KB (3 slots)
  const int lane = threadIdx.x & 63;
  const int wave = threadIdx.x >> 6;
  const int wr = wave >> 2, wc = wave & 3;       // 2 x 4 waves
  // T1: bijective XCD swizzle (all grids here have nwg % 8 == 0)
  const int nwg  = gridDim.x * gridDim.y;
  const int orig = blockIdx.y * gridDim.x + blockIdx.x;
  const int wgid = (orig & 7) * (nwg >> 3) + (orig >> 3);
  const int tn = (wgid % gridDim.x) * 256;
  const int tm = (wgid / gridDim.x) * 128;
  const int z  = blockIdx.z;
  A += (long long)z * sA;
  B += (long long)z * sB;

  const int NT = K >> 6;          // 64-wide K tiles

  // ---- staging geometry (linear LDS dest; source pre-swizzled, rule #21) ----
  const int lr    = lane >> 3;                       // 0..7 row within chunk
  const int lrow  = wave * 8 + lr;                   // row covered by this lane
  const int lslot = ((lane & 7) ^ lr) << 3;          // swizzled k-slot (elements)
  const short* pA = A + (long long)(tm + lrow) * lda + lslot;
  const short* pB = B + (long long)(tn + lrow) * ldb + lslot;
  const long long lda64 = 64LL * lda;
  const long long ldb64 = 64LL * ldb;

  auto stageA = [&](int t, int slot) {
    const long long ko = (long long)t << 6;
    const int db = slot * 8192 + wave * 512;         // shorts
    __builtin_amdgcn_global_load_lds(
        (const __attribute__((address_space(1))) void*)(pA + ko),
        (__attribute__((address_space(3))) void*)(As + db), 16, 0, 0);
    __builtin_amdgcn_global_load_lds(
        (const __attribute__((address_space(1))) void*)(pA + lda64 + ko),
        (__attribute__((address_space(3))) void*)(As + db + 4096), 16, 0, 0);
  };
  auto stageB = [&](int t, int slot) {
    const long long ko = (long long)t << 6;
    const int db = slot * 16384 + wave * 512;        // shorts
    __builtin_amdgcn_global_load_lds(
        (const __attribute__((address_space(1))) void*)(pB + ko),
        (__attribute__((address_space(3))) void*)(Bs + db), 16, 0, 0);
    __builtin_amdgcn_global_load_lds(
        (const __attribute__((address_space(1))) void*)(pB + ldb64 + ko),
        (__attribute__((address_space(3))) void*)(Bs + db + 4096), 16, 0, 0);
    __builtin_amdgcn_global_load_lds(
        (const __attribute__((address_space(1))) void*)(pB + 2*ldb64 + ko),
        (__attribute__((address_space(3))) void*)(Bs + db + 8192), 16, 0, 0);
    __builtin_amdgcn_global_load_lds(
        (const __attribute__((address_space(1))) void*)(pB + 3*ldb64 + ko),
        (__attribute__((address_space(3))) void*)(Bs + db + 12288), 16, 0, 0);
  };

  // ---- LDS read addressing (phys slot = logical slot ^ (row&7)) ----
  const unsigned asB = (unsigned)(unsigned long long)(lds_sp)As;
  const unsigned bsB = (unsigned)(unsigned long long)(lds_sp)Bs;
  const int l15 = lane & 15, l4 = lane >> 4;
  const unsigned offk0 = (unsigned)(( l4      ^ (lane & 7)) << 4);   // bytes
  const unsigned offk1 = (unsigned)(((l4 + 4) ^ (lane & 7)) << 4);
  const unsigned aBase = asB + (unsigned)((wr * 64 + l15) * 128);
  const unsigned bBase = bsB + (unsigned)((wc * 64 + l15) * 128);

  f32x4 acc[4][4] = {};
  u32x4 af[2][2], bfr[4][2];

  // ---- prologue: stage tiles 0 (slot0), 1 (slot1); drain tile 0 ----
  stageB(0, 0); stageA(0, 0);
  stageB(1 < NT ? 1 : 0, 1); stageA(1 < NT ? 1 : 0, 1);
  VM6();
  BARv();

  // ---- main loop: 2 phases / K-tile ----
  int rd = 0;
  #pragma unroll 1
  for (int t = 0; t < NT; ++t) {
    const int st = rd + 2 >= 3 ? rd - 1 : rd + 2;          // (t+2) % 3
    const int tc = t + 2 < NT ? t + 2 : NT - 1;            // tail clamp
    // phase A: A-lo + all B reads; stage next B; MFMA quadrant 0
    RD_A(0, rd); RD_B(rd);
    stageB(tc, st);
    LGKM8();
    BARv(); LGKM0();
    __builtin_amdgcn_s_setprio(1); MM(0); __builtin_amdgcn_s_setprio(0);
    BARv();
    // phase B: A-hi reads; stage next A; counted vmcnt; MFMA quadrant 2
    RD_A(2, rd);
    stageA(tc, st);
    VM6();
    BARv(); LGKM0();
    __builtin_amdgcn_s_setprio(1); MM(2); __builtin_amdgcn_s_setprio(0);
    BARv();
    rd = rd + 1 >= 3 ? 0 : rd + 1;
  }

  // ---- epilogue: C/D layout col=lane&15, row=(lane>>4)*4+j ----
  const int row0 = tm + wr * 64 + l4 * 4;
  const int col0 = tn + wc * 64 + l15;
  #pragma unroll
  for (int mi = 0; mi < 4; ++mi) {
    #pragma unroll
    for (int j = 0; j < 4; ++j) {
      const int row = row0 + mi * 16 + j;
      #pragma unroll
      for (int ni = 0; ni < 4; ++ni) {
        const int col = col0 + ni * 16;
        float v = acc[mi][ni][j];
        if (EPI == 1) {
          ((float*)Cv + (long long)z * sC)[(long long)row * ldc + col] = v;
        } else if (EPI == 0) {
          v += bias[col];
          ((short*)Cv + (long long)z * sC)[(long long)row * ldc + col] = f2bf(v);
        } else if (EPI == 2) {
          v += bias[col];
          v = 0.5f * v * (1.0f + erff(v * 0.70710678118654752f));
          ((short*)Cv + (long long)z * sC)[(long long)row * ldc + col] = f2bf(v);
        } else {
          v += bias[col] + aux[(long long)row * ldc + col];
          ((float*)Cv + (long long)z * sC)[(long long)row * ldc + col] = v;
        }
      }
    }
  }
}

// ---------------------------------------------------------------------------
// LayerNorm: out_bf16[row] = LN(x[row] (+ res[row])) * g + b   (row = 2048 f32)
// ---------------------------------------------------------------------------
__global__ __launch_bounds__(256)
void ln_kernel(const float* __restrict__ x, const float* __restrict__ res,
               const float* __restrict__ g, const float* __restrict__ b,
               short* __restrict__ out, int hasres)
{
  const int row = blockIdx.x;
  const int tid = threadIdx.x;
  const float4* X = (const float4*)x + (long long)row * 512;
  float4 v0 = X[tid], v1 = X[tid + 256];
  if (hasres) {
    const float4* R = (const float4*)res + (long long)row * 512;
    float4 r0 = R[tid], r1 = R[tid + 256];
    v0.x += r0.x; v0.y += r0.y; v0.z += r0.z; v0.w += r0.w;
    v1.x += r1.x; v1.y += r1.y; v1.z += r1.z; v1.w += r1.w;
  }
  float s1 = v0.x + v0.y + v0.z + v0.w + v1.x + v1.y + v1.z + v1.w;
  float s2 = v0.x*v0.x + v0.y*v0.y + v0.z*v0.z + v0.w*v0.w
           + v1.x*v1.x + v1.y*v1.y + v1.z*v1.z + v1.w*v1.w;
  #pragma unroll
  for (int o = 32; o > 0; o >>= 1) { s1 += __shfl_xor(s1, o); s2 += __shfl_xor(s2, o); }
  __shared__ float red[8];
  if ((tid & 63) == 0) { red[tid >> 6] = s1; red[4 + (tid >> 6)] = s2; }
  __syncthreads();
  s1 = red[0] + red[1] + red[2] + red[3];
  s2 = red[4] + red[5] + red[6] + red[7];
  const float mean = s1 * (1.0f / 2048.0f);
  const float var  = s2 * (1.0f / 2048.0f) - mean * mean;
  const float rstd = rsqrtf(var + 1e-5f);
  const float4* G  = (const float4*)g;
  const float4* Bb = (const float4*)b;
  float4 g0 = G[tid], g1 = G[tid + 256], b0 = Bb[tid], b1 = Bb[tid + 256];
  s16x4 o0, o1;
  o0[0] = f2bf((v0.x - mean) * rstd * g0.x + b0.x);
  o0[1] = f2bf((v0.y - mean) * rstd * g0.y + b0.y);
  o0[2] = f2bf((v0.z - mean) * rstd * g0.z + b0.z);
  o0[3] = f2bf((v0.w - mean) * rstd * g0.w + b0.w);
  o1[0] = f2bf((v1.x - mean) * rstd * g1.x + b1.x);
  o1[1] = f2bf((v1.y - mean) * rstd * g1.y + b1.y);
  o1[2] = f2bf((v1.z - mean) * rstd * g1.z + b1.z);
  o1[3] = f2bf((v1.w - mean) * rstd * g1.w + b1.w);
  *(s16x4*)&out[(long long)row * 2048 + tid * 4]        = o0;
  *(s16x4*)&out[(long long)row * 2048 + 1024 + tid * 4] = o1;
}

// ---------------------------------------------------------------------------
// Softmax: probs_bf16 = softmax(scores*scale + mask[q])
// ---------------------------------------------------------------------------
__global__ __launch_bounds__(256)
void softmax_kernel(const float* __restrict__ scores, const float* __restrict__ mask,
                    short* __restrict__ probs)
{
  const long long row = blockIdx.x;          // b*SEQ + q
  const int q  = blockIdx.x & (SEQ_ - 1);
  const int tid = threadIdx.x;
  const float scale = 0.022097086912079608f; // 1/sqrt(2048)
  const float4* S  = (const float4*)scores + row * 512;
  const float4* Mk = (const float4*)mask + (long long)q * 512;
  float4 v0 = S[tid], v1 = S[tid + 256];
  float4 m0 = Mk[tid], m1 = Mk[tid + 256];
  float a[8] = { v0.x*scale + m0.x, v0.y*scale + m0.y, v0.z*scale + m0.z, v0.w*scale + m0.w,
                 v1.x*scale + m1.x, v1.y*scale + m1.y, v1.z*scale + m1.z, v1.w*scale + m1.w };
  float mx = a[0];
  #pragma unroll
  for (int i = 1; i < 8; ++i) mx = fmaxf(mx, a[i]);
  #pragma unroll
  for (int o = 32; o > 0; o >>= 1) mx = fmaxf(mx, __shfl_xor(mx, o));
  __shared__ float red[8];
  if ((tid & 63) == 0) red[tid >> 6] = mx;
  __syncthreads();
  mx = fmaxf(fmaxf(red[0], red[1]), fmaxf(red[2], red[3]));
  float e[8], sum = 0.f;
  #pragma unroll
  for (int i = 0; i < 8; ++i) { e[i] = __expf(a[i] - mx); sum += e[i]; }
  #pragma unroll
  for (int o = 32; o > 0; o >>= 1) sum += __shfl_xor(sum, o);
  if ((tid & 63) == 0) red[4 + (tid >> 6)] = sum;
  __syncthreads();
  sum = red[4] + red[5] + red[6] + red[7];
  const float inv = 1.0f / sum;
  s16x4 o0, o1;
  #pragma unroll
  for (int i = 0; i < 4; ++i) o0[i] = f2bf(e[i] * inv);
  #pragma unroll
  for (int i = 0; i < 4; ++i) o1[i] = f2bf(e[4 + i] * inv);
  probs += row * 2048;
  *(s16x4*)&probs[tid * 4]        = o0;
  *(s16x4*)&probs[1024 + tid * 4] = o1;
}

// ---------------------------------------------------------------------------
// fp32 (R,C) -> bf16 (C,R) transpose-convert (weights)
// ---------------------------------------------------------------------------
__global__ __launch_bounds__(256)
void cvt_transpose_kernel(const float* __restrict__ in, short* __restrict__ out,
                          int R, int C)
{
  __shared__ float t[32][33];
  const int tx = threadIdx.x & 31, ty = threadIdx.x >> 5;
  const int r0 = blockIdx.y << 5, c0 = blockIdx.x << 5;
  #pragma unroll
  for (int i = 0; i < 32; i += 8)
    t[ty + i][tx] = in[(long long)(r0 + ty + i) * C + c0 + tx];
  __syncthreads();
  #pragma unroll
  for (int i = 0; i < 32; i += 8)
    out[(long long)(c0 + ty + i) * R + r0 + tx] = f2bf(t[tx][ty + i]);
}

// bf16 strided (z,R,C) -> (z,C,R) transpose (V)
__global__ __launch_bounds__(256)
void transpose_bf16_kernel(const short* __restrict__ in, short* __restrict__ out,
                           int ldin, int ldout, long long sin_, long long sout_)
{
  __shared__ short t[32][33];
  in  += (long long)blockIdx.z * sin_;
  out += (long long)blockIdx.z * sout_;
  const int tx = threadIdx.x & 31, ty = threadIdx.x >> 5;
  const int r0 = blockIdx.y << 5, c0 = blockIdx.x << 5;
  #pragma unroll
  for (int i = 0; i < 32; i += 8)
    t[ty + i][tx] = in[(long long)(r0 + ty + i) * ldin + c0 + tx];
  __syncthreads();
  #pragma unroll
  for (int i = 0; i < 32; i += 8)
    out[(long long)(c0 + ty + i) * ldout + r0 + tx] = t[tx][ty + i];
}

__global__ __launch_bounds__(256)
void concat_bias_kernel(const float* a, const float* b, const float* c, float* o)
{
  const int i = blockIdx.x * 256 + threadIdx.x;   // 6144
  o[i] = i < 2048 ? a[i] : (i < 4096 ? b[i - 2048] : c[i - 4096]);
}

// ---------------------------------------------------------------------------
extern "C" void kernel_launch(void* const* d_in, const int* in_sizes, int n_in,
                              void* d_out, int out_size, void* d_ws, size_t ws_size,
                              hipStream_t stream)
{
  const float* x    = (const float*)d_in[0];
  const float* mask = (const float*)d_in[1];
  const float* wq   = (const float*)d_in[4];
  const float* bq   = (const float*)d_in[5];
  const float* wk   = (const float*)d_in[6];
  const float* bk   = (const float*)d_in[7];
  const float* wv   = (const float*)d_in[8];
  const float* bv   = (const float*)d_in[9];
  const float* g1   = (const float*)d_in[10];
  const float* b1   = (const float*)d_in[11];
  const float* g2   = (const float*)d_in[12];
  const float* b2   = (const float*)d_in[13];
  const float* w1   = (const float*)d_in[14];
  const float* bw1  = (const float*)d_in[15];
  const float* w2   = (const float*)d_in[16];
  const float* bw2  = (const float*)d_in[17];
  float* out = (float*)d_out;

  char* p = (char*)d_ws;
  auto take = [&](size_t bytes) { char* r = p; p += (bytes + 255) & ~(size_t)255; return r; };
  short* wqkvT = (short*)take((size_t)3 * DIM_ * DIM_ * 2);  // [6144][2048] bf16
  short* w1T   = (short*)take((size_t)DIM_ * HID_ * 2);      // [8192][2048]
  short* w2T   = (short*)take((size_t)HID_ * DIM_ * 2);      // [2048][8192]
  short* h_bf  = (short*)take((size_t)TOK_ * DIM_ * 2);      // reused as h2
  short* qkv   = (short*)take((size_t)TOK_ * 3 * DIM_ * 2);  // [4096][6144]
  short* vT    = (short*)take((size_t)BATCH_ * DIM_ * SEQ_ * 2);
  float* scores= (float*)take((size_t)BATCH_ * SEQ_ * SEQ_ * 4); // reused as attn_out
  short* attn  = (short*)take((size_t)BATCH_ * SEQ_ * SEQ_ * 2);
  float* cbias = (float*)take((size_t)3 * DIM_ * 4);
  short* ffn1  = qkv;          // 64MB alias over qkv+vT (dead after PV)
  float* attno = scores;       // alias (scores dead after softmax)
  short* h2    = h_bf;         // alias (h dead after QKV)

  const dim3 blk(256), gblk(512);
  // weight convert+transpose
  cvt_transpose_kernel<<<dim3(DIM_/32, DIM_/32), blk, 0, stream>>>(wq, wqkvT, DIM_, DIM_);
  cvt_transpose_kernel<<<dim3(DIM_/32, DIM_/32), blk, 0, stream>>>(wk, wqkvT + (size_t)DIM_*DIM_, DIM_, DIM_);
  cvt_transpose_kernel<<<dim3(DIM_/32, DIM_/32), blk, 0, stream>>>(wv, wqkvT + (size_t)2*DIM_*DIM_, DIM_, DIM_);
  cvt_transpose_kernel<<<dim3(HID_/32, DIM_/32), blk, 0, stream>>>(w1, w1T, DIM_, HID_);
  cvt_transpose_kernel<<<dim3(DIM_/32, HID_/32), blk, 0, stream>>>(w2, w2T, HID_, DIM_);
  concat_bias_kernel<<<24, blk, 0, stream>>>(bq, bk, bv, cbias);
  // LN1
  ln_kernel<<<TOK_, blk, 0, stream>>>(x, nullptr, g1, b1, h_bf, 0);
  // fused QKV: [4096,2048] @ [6144,2048]^T -> qkv bf16 [4096][6144]
  gemm8p<0><<<dim3(6144/256, TOK_/128, 1), gblk, 0, stream>>>(
      h_bf, wqkvT, qkv, cbias, nullptr, TOK_, 6144, DIM_, DIM_, DIM_, 6144, 0, 0, 0);
  // scores = q @ k^T (batched)
  gemm8p<1><<<dim3(SEQ_/256, SEQ_/128, BATCH_), gblk, 0, stream>>>(
      qkv, qkv + DIM_, scores, nullptr, nullptr, SEQ_, SEQ_, DIM_, 6144, 6144, SEQ_,
      (long long)SEQ_ * 6144, (long long)SEQ_ * 6144, (long long)SEQ_ * SEQ_);
  // softmax -> bf16 probs
  softmax_kernel<<<BATCH_ * SEQ_, blk, 0, stream>>>(scores, mask, attn);
  // V transpose: (B,S,D) strided in qkv -> vT (B,D,S)
  transpose_bf16_kernel<<<dim3(DIM_/32, SEQ_/32, BATCH_), blk, 0, stream>>>(
      qkv + 2*DIM_, vT, 6144, SEQ_, (long long)SEQ_ * 6144, (long long)DIM_ * SEQ_);
  // attn_out = probs @ V
  gemm8p<1><<<dim3(DIM_/256, SEQ_/128, BATCH_), gblk, 0, stream>>>(
      attn, vT, attno, nullptr, nullptr, SEQ_, DIM_, SEQ_, SEQ_, SEQ_, DIM_,
      (long long)SEQ_ * SEQ_, (long long)DIM_ * SEQ_, (long long)SEQ_ * DIM_);
  // LN2 over x + attn_out
  ln_kernel<<<TOK_, blk, 0, stream>>>(x, attno, g2, b2, h2, 1);
  // FFN1: gelu(h2 @ w1 + b1) -> bf16
  gemm8p<2><<<dim3(HID_/256, TOK_/128, 1), gblk, 0, stream>>>(
      h2, w1T, ffn1, bw1, nullptr, TOK_, HID_, DIM_, DIM_, DIM_, HID_, 0, 0, 0);
  // FFN2: x + (ffn1 @ w2 + b2) -> fp32 d_out
  gemm8p<3><<<dim3(DIM_/256, TOK_/128, 1), gblk, 0, stream>>>(
      ffn1, w2T, out, bw2, x, TOK_, DIM_, HID_, HID_, HID_, DIM_, 0, 0, 0);
}